// Round 1
// baseline (270.308 us; speedup 1.0000x reference)
//
#include <hip/hip_runtime.h>
#include <hip/hip_bf16.h>
#include <stdint.h>

// EdgeDecoder: out = relu(concat(zd[row], zt[col]) @ W1 + b1) @ W2 + b2
// Strategy: prep kernels convert zd/zt -> bf16 and W1 -> bf16 transposed [n][k]
// into d_ws; main kernel is a fused gather-GEMM-reduce using
// mfma_f32_16x16x32_bf16 with global_load_lds(16B) staging and XOR-swizzled LDS.

typedef unsigned short u16;
typedef __attribute__((ext_vector_type(8))) short short8;
typedef __attribute__((ext_vector_type(4))) float f32x4;

#define HDIM 256
#define KDIM 512
#define BM 64      // edges per block
#define BK 64      // k-chunk
#define NWAVE 4

__device__ __forceinline__ u16 f2bf(float f) {
  union { float f; uint32_t u; } v; v.f = f;
  uint32_t u = v.u;
  return (u16)((u + 0x7fffu + ((u >> 16) & 1u)) >> 16);   // RNE, inputs finite
}

// async global->LDS, 16B per lane; LDS dest must be wave-uniform base (+lane*16)
__device__ __forceinline__ void gl2lds16(const void* g, void* l) {
  __builtin_amdgcn_global_load_lds(
      (const __attribute__((address_space(1))) unsigned int*)g,
      (__attribute__((address_space(3))) unsigned int*)l,
      16, 0, 0);
}

__global__ void cvt_bf16_kernel(const float* __restrict__ src,
                                u16* __restrict__ dst, int n4) {
  int i = blockIdx.x * blockDim.x + threadIdx.x;
  if (i >= n4) return;
  float4 v = ((const float4*)src)[i];
  ushort4 o;
  o.x = f2bf(v.x); o.y = f2bf(v.y); o.z = f2bf(v.z); o.w = f2bf(v.w);
  ((ushort4*)dst)[i] = o;
}

// W1 [512][256] row-major fp32 -> W1T [256][512] bf16 (n-major, k contiguous)
__global__ void w1t_kernel(const float* __restrict__ w1, u16* __restrict__ w1t) {
  int t = blockIdx.x * blockDim.x + threadIdx.x;  // 131072 threads
  int n = t >> 9, k = t & 511;
  w1t[n * 512 + k] = f2bf(w1[k * 256 + n]);
}

// Main fused kernel. Block = 256 thr (4 waves). Tile: 64 edges x 256 cols,
// wave w owns cols [w*64, w*64+64). K-loop: 8 chunks of BK=64
// (chunks 0-3 gather from zd[row], 4-7 from zt[col]).
__global__ __launch_bounds__(256, 2) void edge_mlp_kernel(
    const u16* __restrict__ zd, const u16* __restrict__ zt,
    const int* __restrict__ row, const int* __restrict__ col,
    const u16* __restrict__ w1t, const float* __restrict__ b1,
    const float* __restrict__ w2, const float* __restrict__ b2,
    float* __restrict__ out, int E) {
  __shared__ u16 lA[BM * BK];      // 8KB  [edge][k], 16B-slot XOR-swizzled
  __shared__ u16 lB[HDIM * BK];    // 32KB [n][k],   16B-slot XOR-swizzled
  __shared__ float lP[NWAVE * BM]; // 1KB per-wave layer-2 partials

  const int tid  = threadIdx.x;
  const int wid  = tid >> 6;
  const int lane = tid & 63;
  const int e0   = blockIdx.x * BM;

  // A-staging: wave w stages edges [w*16, w*16+16); this lane covers local
  // edges eA (issue 0) and eA+8 (issue 1), 16B slot (lane&7), swizzled.
  const int eA = wid * 16 + (lane >> 3);
  const int g1 = min(e0 + eA, E - 1);
  const int g2 = min(e0 + eA + 8, E - 1);
  const int slog = ((lane & 7) ^ ((lane >> 3) & 7)) * 8;  // swizzled elem offset

  const u16* pD1 = zd + (size_t)row[g1] * HDIM + slog;
  const u16* pT1 = zt + (size_t)col[g1] * HDIM + slog;
  const u16* pD2 = zd + (size_t)row[g2] * HDIM + slog;
  const u16* pT2 = zt + (size_t)col[g2] * HDIM + slog;
  // B-staging: wave w stages exactly its own n-rows [w*64, w*64+64)
  const u16* pB = w1t + (size_t)(wid * 64 + (lane >> 3)) * KDIM + slog;

  u16* lA1 = &lA[(wid * 16) * BK];        // wave-uniform LDS bases
  u16* lA2 = &lA[(wid * 16 + 8) * BK];
  u16* lBw = &lB[(wid * 64) * BK];

  f32x4 acc[4][4];
#pragma unroll
  for (int i = 0; i < 4; ++i)
#pragma unroll
    for (int j = 0; j < 4; ++j) acc[i][j] = f32x4{0.f, 0.f, 0.f, 0.f};

  const int colid = lane & 15;
  const int quad  = lane >> 4;
  const int csw   = colid & 7;            // read-side swizzle key (e&7 == n&7 == colid&7)

  for (int kc = 0; kc < 8; ++kc) {
    const int koff = kc * BK;
    const u16* s1 = (kc < 4) ? (pD1 + koff) : (pT1 + (koff - HDIM));
    const u16* s2 = (kc < 4) ? (pD2 + koff) : (pT2 + (koff - HDIM));

    __syncthreads();                       // prev reads done before overwrite
    gl2lds16(s1, lA1);
    gl2lds16(s2, lA2);
#pragma unroll
    for (int j = 0; j < 8; ++j)
      gl2lds16(pB + (size_t)j * 8 * KDIM + koff, lBw + j * 8 * BK);
    __syncthreads();                       // drains vmcnt -> staged data visible

#pragma unroll
    for (int ks = 0; ks < BK; ks += 32) {
      const int sl = (ks >> 3) + quad;     // logical 16B slot
      short8 aF[4], bF[4];
#pragma unroll
      for (int rt = 0; rt < 4; ++rt)
        aF[rt] = *(const short8*)&lA[(rt * 16 + colid) * BK + ((sl ^ csw) * 8)];
#pragma unroll
      for (int ct = 0; ct < 4; ++ct)
        bF[ct] = *(const short8*)&lB[(wid * 64 + ct * 16 + colid) * BK + ((sl ^ csw) * 8)];
#pragma unroll
      for (int rt = 0; rt < 4; ++rt)
#pragma unroll
        for (int ct = 0; ct < 4; ++ct)
          acc[rt][ct] = __builtin_amdgcn_mfma_f32_16x16x32_bf16(
              aF[rt], bF[ct], acc[rt][ct], 0, 0, 0);
    }
  }

  // Epilogue: h = relu(acc + b1[n]); partial[e] = sum_n h*W2[n] (fp32 end-to-end)
  // C/D layout: n = wave*64 + ct*16 + (lane&15), e = rt*16 + quad*4 + j
  float b1v[4], w2v[4];
#pragma unroll
  for (int ct = 0; ct < 4; ++ct) {
    int n = wid * 64 + ct * 16 + colid;
    b1v[ct] = b1[n];
    w2v[ct] = w2[n];
  }
  float p[4][4];
#pragma unroll
  for (int rt = 0; rt < 4; ++rt)
#pragma unroll
    for (int j = 0; j < 4; ++j) {
      float s = 0.f;
#pragma unroll
      for (int ct = 0; ct < 4; ++ct)
        s += fmaxf(acc[rt][ct][j] + b1v[ct], 0.f) * w2v[ct];
      // butterfly over the 16 lanes of this quad (sums over n within wave)
#pragma unroll
      for (int off = 8; off >= 1; off >>= 1)
        s += __shfl_xor(s, off, 16);
      p[rt][j] = s;
    }
  if (colid == 0) {
#pragma unroll
    for (int rt = 0; rt < 4; ++rt)
#pragma unroll
      for (int j = 0; j < 4; ++j)
        lP[wid * BM + rt * 16 + quad * 4 + j] = p[rt][j];
  }
  __syncthreads();
  if (tid < BM) {
    int ge = e0 + tid;
    if (ge < E)
      out[ge] = lP[tid] + lP[BM + tid] + lP[2 * BM + tid] + lP[3 * BM + tid]
                + b2[0];
  }
}

// Correct-but-slow fp32 fallback (only if ws_size < 36.2MB): 16 edges/block.
__global__ void fallback_kernel(
    const float* __restrict__ zd, const float* __restrict__ zt,
    const int* __restrict__ row, const int* __restrict__ col,
    const float* __restrict__ W1, const float* __restrict__ b1,
    const float* __restrict__ W2, const float* __restrict__ b2,
    float* __restrict__ out, int E) {
  __shared__ float zc[16][512];
  __shared__ float red[4][16];
  const int e0 = blockIdx.x * 16;
  const int tid = threadIdx.x;
  for (int i = tid; i < 16 * 512; i += 256) {
    int e = i >> 9, k = i & 511;
    int ge = min(e0 + e, E - 1);
    zc[e][k] = (k < HDIM) ? zd[(size_t)row[ge] * HDIM + k]
                          : zt[(size_t)col[ge] * HDIM + (k - HDIM)];
  }
  __syncthreads();
  float acc[16];
#pragma unroll
  for (int e = 0; e < 16; ++e) acc[e] = 0.f;
  for (int k = 0; k < KDIM; ++k) {
    float w = W1[k * HDIM + tid];
#pragma unroll
    for (int e = 0; e < 16; ++e) acc[e] += zc[e][k] * w;
  }
  float wv = W2[tid], bv = b1[tid];
  const int lane = tid & 63, wid = tid >> 6;
#pragma unroll
  for (int e = 0; e < 16; ++e) {
    float pv = fmaxf(acc[e] + bv, 0.f) * wv;
#pragma unroll
    for (int off = 32; off >= 1; off >>= 1) pv += __shfl_down(pv, off, 64);
    if (lane == 0) red[wid][e] = pv;
  }
  __syncthreads();
  if (tid < 16) {
    int ge = e0 + tid;
    if (ge < E)
      out[ge] = red[0][tid] + red[1][tid] + red[2][tid] + red[3][tid] + b2[0];
  }
}

extern "C" void kernel_launch(void* const* d_in, const int* in_sizes, int n_in,
                              void* d_out, int out_size, void* d_ws, size_t ws_size,
                              hipStream_t stream) {
  const float* zd_f = (const float*)d_in[0];
  const float* zt_f = (const float*)d_in[1];
  const int*   row  = (const int*)d_in[2];
  const int*   col  = (const int*)d_in[3];
  const float* W1   = (const float*)d_in[4];
  const float* b1   = (const float*)d_in[5];
  const float* W2   = (const float*)d_in[6];
  const float* b2   = (const float*)d_in[7];
  float* out = (float*)d_out;

  const int E  = in_sizes[2];            // 500000
  const int ND = in_sizes[0] / HDIM;     // 50000
  const int NT = in_sizes[1] / HDIM;     // 20000

  size_t off_w1t = 0;                                    // 256KB
  size_t off_zd  = (size_t)KDIM * HDIM * sizeof(u16);
  size_t off_zt  = off_zd + (size_t)ND * HDIM * sizeof(u16);
  size_t need    = off_zt + (size_t)NT * HDIM * sizeof(u16);  // ~36.1MB

  if (ws_size >= need) {
    u16* w1t = (u16*)((char*)d_ws + off_w1t);
    u16* zdb = (u16*)((char*)d_ws + off_zd);
    u16* ztb = (u16*)((char*)d_ws + off_zt);
    int n4d = ND * HDIM / 4, n4t = NT * HDIM / 4;
    cvt_bf16_kernel<<<(n4d + 255) / 256, 256, 0, stream>>>(zd_f, zdb, n4d);
    cvt_bf16_kernel<<<(n4t + 255) / 256, 256, 0, stream>>>(zt_f, ztb, n4t);
    w1t_kernel<<<(KDIM * HDIM + 255) / 256, 256, 0, stream>>>(W1, w1t);
    edge_mlp_kernel<<<(E + BM - 1) / BM, 256, 0, stream>>>(
        zdb, ztb, row, col, w1t, b1, W2, b2, out, E);
  } else {
    fallback_kernel<<<(E + 15) / 16, 256, 0, stream>>>(
        zd_f, zt_f, row, col, W1, b1, W2, b2, out, E);
  }
}

// Round 2
// 268.061 us; speedup vs baseline: 1.0084x; 1.0084x over previous
//
#include <hip/hip_runtime.h>
#include <hip/hip_bf16.h>
#include <stdint.h>

// EdgeDecoder: out = relu(concat(zd[row], zt[col]) @ W1 + b1) @ W2 + b2
// R2: single fused prep kernel (LDS-tiled W1 transpose + grid-stride bf16 cvt),
// main kernel widened to BM=128 edges/block (RT=8) to balance LDS-read pipe
// (12 ds_read_b128 per ks-step) against matrix pipe (32 MFMA per ks-step).

typedef unsigned short u16;
typedef __attribute__((ext_vector_type(8))) short short8;
typedef __attribute__((ext_vector_type(4))) float f32x4;

#define HDIM 256
#define KDIM 512
#define BM 128     // edges per block
#define BK 64      // k-chunk
#define NWAVE 4

__device__ __forceinline__ u16 f2bf(float f) {
  union { float f; uint32_t u; } v; v.f = f;
  uint32_t u = v.u;
  return (u16)((u + 0x7fffu + ((u >> 16) & 1u)) >> 16);   // RNE, inputs finite
}

// async global->LDS, 16B per lane; LDS dest must be wave-uniform base (+lane*16)
__device__ __forceinline__ void gl2lds16(const void* g, void* l) {
  __builtin_amdgcn_global_load_lds(
      (const __attribute__((address_space(1))) unsigned int*)g,
      (__attribute__((address_space(3))) unsigned int*)l,
      16, 0, 0);
}

// One prep kernel: blocks 0..31 do a 64x64 LDS-tiled transpose of W1
// (512x256 fp32 -> W1T 256x512 bf16, coalesced both sides); remaining blocks
// grid-stride-convert zd then zt to bf16 via float4 loads.
#define CVT_BLOCKS 4096
__global__ void prep_kernel(const float* __restrict__ zd_f,
                            const float* __restrict__ zt_f,
                            const float* __restrict__ w1,
                            u16* __restrict__ zdb, u16* __restrict__ ztb,
                            u16* __restrict__ w1t, int n4d, int n4t) {
  const int b = blockIdx.x;
  if (b < 32) {
    __shared__ float tile[64][65];
    const int k0 = (b >> 2) * 64, n0 = (b & 3) * 64;
    const int tx = threadIdx.x & 63, ty = threadIdx.x >> 6;
#pragma unroll
    for (int i = ty; i < 64; i += 4)
      tile[i][tx] = w1[(size_t)(k0 + i) * HDIM + n0 + tx];   // coalesced 256B
    __syncthreads();
#pragma unroll
    for (int i = ty; i < 64; i += 4)
      w1t[(size_t)(n0 + i) * KDIM + k0 + tx] = f2bf(tile[tx][i]);  // coalesced
  } else {
    const int idx = (b - 32) * 256 + threadIdx.x;
    const int stride = CVT_BLOCKS * 256;
    for (int i = idx; i < n4d; i += stride) {
      float4 v = ((const float4*)zd_f)[i];
      ushort4 o; o.x = f2bf(v.x); o.y = f2bf(v.y); o.z = f2bf(v.z); o.w = f2bf(v.w);
      ((ushort4*)zdb)[i] = o;
    }
    for (int i = idx; i < n4t; i += stride) {
      float4 v = ((const float4*)zt_f)[i];
      ushort4 o; o.x = f2bf(v.x); o.y = f2bf(v.y); o.z = f2bf(v.z); o.w = f2bf(v.w);
      ((ushort4*)ztb)[i] = o;
    }
  }
}

// Main fused kernel. Block = 256 thr (4 waves). Tile: 128 edges x 256 cols,
// wave w owns cols [w*64, w*64+64) across all 128 edges (8x4 16x16 frags).
// K-loop: 8 chunks of BK=64 (chunks 0-3 gather zd[row], 4-7 zt[col]).
__global__ __launch_bounds__(256, 2) void edge_mlp_kernel(
    const u16* __restrict__ zd, const u16* __restrict__ zt,
    const int* __restrict__ row, const int* __restrict__ col,
    const u16* __restrict__ w1t, const float* __restrict__ b1,
    const float* __restrict__ w2, const float* __restrict__ b2,
    float* __restrict__ out, int E) {
  __shared__ u16 lA[BM * BK];      // 16KB [edge][k], 16B-slot XOR-swizzled
  __shared__ u16 lB[HDIM * BK];    // 32KB [n][k],    16B-slot XOR-swizzled
  __shared__ float lP[NWAVE * BM]; // 2KB per-wave layer-2 partials

  const int tid  = threadIdx.x;
  const int wid  = tid >> 6;
  const int lane = tid & 63;
  const int e0   = blockIdx.x * BM;
  const int r8   = lane >> 3;                      // row-in-8-group per issue
  const int slog = ((lane & 7) ^ (r8 & 7)) * 8;    // swizzled 16B-slot offset

  // A-staging: wave w stages edges [w*32, w*32+32) in 4 issues of 8 rows.
  uint32_t offD[4], offT[4];
#pragma unroll
  for (int t = 0; t < 4; ++t) {
    int ge = min(e0 + wid * 32 + r8 + 8 * t, E - 1);
    offD[t] = (uint32_t)row[ge] * HDIM;
    offT[t] = (uint32_t)col[ge] * HDIM;
  }
  // B-staging: wave w stages its own n-rows [w*64, w*64+64) in 8 issues.
  const u16* pB = w1t + (uint32_t)(wid * 64 + r8) * KDIM + slog;

  u16* lAw = &lA[(wid * 32) * BK];   // wave-uniform LDS bases
  u16* lBw = &lB[(wid * 64) * BK];

  f32x4 acc[8][4];
#pragma unroll
  for (int i = 0; i < 8; ++i)
#pragma unroll
    for (int j = 0; j < 4; ++j) acc[i][j] = f32x4{0.f, 0.f, 0.f, 0.f};

  const int colid = lane & 15;
  const int quad  = lane >> 4;
  const int csw   = colid & 7;       // read-side swizzle key (row&7 == colid&7)

  for (int kc = 0; kc < 8; ++kc) {
    const int koff = (kc & 3) * BK;  // k-offset within the zd/zt row
    const u16* zbase = (kc < 4) ? zd : zt;

    __syncthreads();                 // prev reads done before overwrite
#pragma unroll
    for (int t = 0; t < 4; ++t) {
      uint32_t o = (kc < 4) ? offD[t] : offT[t];
      gl2lds16(zbase + o + koff + slog, lAw + (8 * t) * BK);
    }
#pragma unroll
    for (int j = 0; j < 8; ++j)
      gl2lds16(pB + (size_t)j * 8 * KDIM + kc * BK, lBw + j * 8 * BK);
    __syncthreads();                 // drains vmcnt -> staged data visible

#pragma unroll
    for (int ks = 0; ks < BK; ks += 32) {
      const int sl = (ks >> 3) + quad;           // logical 16B slot
      short8 aF[8], bF[4];
#pragma unroll
      for (int rt = 0; rt < 8; ++rt)
        aF[rt] = *(const short8*)&lA[(rt * 16 + colid) * BK + ((sl ^ csw) * 8)];
#pragma unroll
      for (int ct = 0; ct < 4; ++ct)
        bF[ct] = *(const short8*)&lB[(wid * 64 + ct * 16 + colid) * BK + ((sl ^ csw) * 8)];
#pragma unroll
      for (int rt = 0; rt < 8; ++rt)
#pragma unroll
        for (int ct = 0; ct < 4; ++ct)
          acc[rt][ct] = __builtin_amdgcn_mfma_f32_16x16x32_bf16(
              aF[rt], bF[ct], acc[rt][ct], 0, 0, 0);
    }
  }

  // Epilogue: h = relu(acc + b1[n]); partial[e] = sum_n h*W2[n] (fp32)
  // C/D layout: n = wid*64 + ct*16 + colid, e = rt*16 + quad*4 + j
  float b1v[4], w2v[4];
#pragma unroll
  for (int ct = 0; ct < 4; ++ct) {
    int n = wid * 64 + ct * 16 + colid;
    b1v[ct] = b1[n];
    w2v[ct] = w2[n];
  }
#pragma unroll
  for (int rt = 0; rt < 8; ++rt)
#pragma unroll
    for (int j = 0; j < 4; ++j) {
      float s = 0.f;
#pragma unroll
      for (int ct = 0; ct < 4; ++ct)
        s += fmaxf(acc[rt][ct][j] + b1v[ct], 0.f) * w2v[ct];
#pragma unroll
      for (int off = 8; off >= 1; off >>= 1)
        s += __shfl_xor(s, off, 16);             // sum over n within quad-row
      if (colid == 0)
        lP[wid * BM + rt * 16 + quad * 4 + j] = s;
    }
  __syncthreads();
  if (tid < BM) {
    int ge = e0 + tid;
    if (ge < E)
      out[ge] = lP[tid] + lP[BM + tid] + lP[2 * BM + tid] + lP[3 * BM + tid]
                + b2[0];
  }
}

// Correct-but-slow fp32 fallback (only if ws_size < 36.2MB): 16 edges/block.
__global__ void fallback_kernel(
    const float* __restrict__ zd, const float* __restrict__ zt,
    const int* __restrict__ row, const int* __restrict__ col,
    const float* __restrict__ W1, const float* __restrict__ b1,
    const float* __restrict__ W2, const float* __restrict__ b2,
    float* __restrict__ out, int E) {
  __shared__ float zc[16][512];
  __shared__ float red[4][16];
  const int e0 = blockIdx.x * 16;
  const int tid = threadIdx.x;
  for (int i = tid; i < 16 * 512; i += 256) {
    int e = i >> 9, k = i & 511;
    int ge = min(e0 + e, E - 1);
    zc[e][k] = (k < HDIM) ? zd[(size_t)row[ge] * HDIM + k]
                          : zt[(size_t)col[ge] * HDIM + (k - HDIM)];
  }
  __syncthreads();
  float acc[16];
#pragma unroll
  for (int e = 0; e < 16; ++e) acc[e] = 0.f;
  for (int k = 0; k < KDIM; ++k) {
    float w = W1[k * HDIM + tid];
#pragma unroll
    for (int e = 0; e < 16; ++e) acc[e] += zc[e][k] * w;
  }
  float wv = W2[tid], bv = b1[tid];
  const int lane = tid & 63, wid = tid >> 6;
#pragma unroll
  for (int e = 0; e < 16; ++e) {
    float pv = fmaxf(acc[e] + bv, 0.f) * wv;
#pragma unroll
    for (int off = 32; off >= 1; off >>= 1) pv += __shfl_down(pv, off, 64);
    if (lane == 0) red[wid][e] = pv;
  }
  __syncthreads();
  if (tid < 16) {
    int ge = e0 + tid;
    if (ge < E)
      out[ge] = red[0][tid] + red[1][tid] + red[2][tid] + red[3][tid] + b2[0];
  }
}

extern "C" void kernel_launch(void* const* d_in, const int* in_sizes, int n_in,
                              void* d_out, int out_size, void* d_ws, size_t ws_size,
                              hipStream_t stream) {
  const float* zd_f = (const float*)d_in[0];
  const float* zt_f = (const float*)d_in[1];
  const int*   row  = (const int*)d_in[2];
  const int*   col  = (const int*)d_in[3];
  const float* W1   = (const float*)d_in[4];
  const float* b1   = (const float*)d_in[5];
  const float* W2   = (const float*)d_in[6];
  const float* b2   = (const float*)d_in[7];
  float* out = (float*)d_out;

  const int E  = in_sizes[2];            // 500000
  const int ND = in_sizes[0] / HDIM;     // 50000
  const int NT = in_sizes[1] / HDIM;     // 20000

  size_t off_w1t = 0;                                    // 256KB
  size_t off_zd  = (size_t)KDIM * HDIM * sizeof(u16);
  size_t off_zt  = off_zd + (size_t)ND * HDIM * sizeof(u16);
  size_t need    = off_zt + (size_t)NT * HDIM * sizeof(u16);  // ~36.1MB

  if (ws_size >= need) {
    u16* w1t = (u16*)((char*)d_ws + off_w1t);
    u16* zdb = (u16*)((char*)d_ws + off_zd);
    u16* ztb = (u16*)((char*)d_ws + off_zt);
    int n4d = ND * HDIM / 4, n4t = NT * HDIM / 4;
    prep_kernel<<<32 + CVT_BLOCKS, 256, 0, stream>>>(zd_f, zt_f, W1,
                                                     zdb, ztb, w1t, n4d, n4t);
    edge_mlp_kernel<<<(E + BM - 1) / BM, 256, 0, stream>>>(
        zdb, ztb, row, col, w1t, b1, W2, b2, out, E);
  } else {
    fallback_kernel<<<(E + 15) / 16, 256, 0, stream>>>(
        zd_f, zt_f, row, col, W1, b1, W2, b2, out, E);
  }
}